// Round 14
// baseline (234.432 us; speedup 1.0000x reference)
//
#include <hip/hip_runtime.h>
#include <hip/hip_bf16.h>

// N=50000, F=256, E=800000, H=4, P=65
#define K_DIM 256
#define RQ    512          // qkb row stride in bf16 elems (1024 B): [q 4x64 | k 4x64]
#define NPAD  640          // GEMM col padding: 5 panels of 128
#define GBM 128
#define GBN 128
#define GBK 32
#define EPITCH 152         // epilogue LDS pitch (elems)
#define NBK   104          // buckets: 8 regions x 13 src-sub (1024-node)  [r8-proven]
#define CBLK  256          // count/scatter blocks
#define SBAND 12512        // src band size (4 bands)
#define DBAND 25024        // dst band size (2 bands)

typedef unsigned short u16;
using short8  = __attribute__((ext_vector_type(8))) short;
using ushort8 = __attribute__((ext_vector_type(8))) unsigned short;
using f32x4   = __attribute__((ext_vector_type(4))) float;
using f32x2   = __attribute__((ext_vector_type(2))) float;

__device__ __forceinline__ float asf(unsigned u) {
  union { unsigned i; float f; } x; x.i = u; return x.f;
}
__device__ __forceinline__ u16 f2b(float f) {
  __hip_bfloat16 h = __float2bfloat16(f); return *(u16*)&h;
}
__device__ __forceinline__ u16 f2h(float f) { _Float16 h = (_Float16)f; return *(u16*)&h; }
__device__ __forceinline__ float h2f(u16 u) { _Float16 h = *(_Float16*)&u; return (float)h; }

// region-major bucket: (src_band*2 + dst_band)*13 + src_sub   [r8-proven]
__device__ __forceinline__ int bucket_of(int s, int d) {
  int sband = s / SBAND;                  // 0..3
  int dband = d / DBAND;                  // 0..1
  int ssub  = (s - sband * SBAND) >> 10;  // 0..12
  return ((sband << 1) | dband) * 13 + ssub;
}

// stored column p -> original W row c, or -1 for pad
__device__ __forceinline__ int map2(int p) {
  if (p < 256) return (p >> 6) * 130 + (p & 63);
  if (p < 512) { int q = p - 256; return (q >> 6) * 130 + 65 + (q & 63); }
  if (p < 516) return (p - 512) * 130 + 64;
  if (p < 520) return (p - 516) * 130 + 129;
  return -1;
}

// Fused: convert_x | convert_w(+bias) | bucket histogram  (denom zeroed by memset)
__global__ void __launch_bounds__(256) prep(
    const float* __restrict__ x, const float* __restrict__ W,
    const float* __restrict__ bv, const int* __restrict__ ei,
    u16* __restrict__ xb, u16* __restrict__ wb,
    float* __restrict__ bias, int* __restrict__ counts,
    int M, int Mpad, int E, int per, int xblocks, int wblocks)
{
  __shared__ int h[NBK];
  const int blk = blockIdx.x, tid = threadIdx.x;
  if (blk < xblocks) {
    int idx = blk * 256 + tid;
    int total = Mpad * (K_DIM / 8);
    if (idx >= total) return;
    int row = idx / (K_DIM / 8);
    ushort8 o;
    if (row < M) {
      const float* s = x + (size_t)idx * 8;
      float4 a = *(const float4*)s;
      float4 b = *(const float4*)(s + 4);
      o[0] = f2b(a.x); o[1] = f2b(a.y); o[2] = f2b(a.z); o[3] = f2b(a.w);
      o[4] = f2b(b.x); o[5] = f2b(b.y); o[6] = f2b(b.z); o[7] = f2b(b.w);
    } else {
      #pragma unroll
      for (int j = 0; j < 8; ++j) o[j] = 0;
    }
    *(ushort8*)(xb + (size_t)idx * 8) = o;
  } else if (blk < xblocks + wblocks) {
    int idx = (blk - xblocks) * 256 + tid;
    int total = NPAD * (K_DIM / 8);
    if (idx >= total) return;
    int p  = idx / (K_DIM / 8);
    int kc = (idx % (K_DIM / 8)) * 8;
    int c  = map2(p);
    ushort8 o;
    if (c >= 0) {
      const float* s = W + (size_t)c * K_DIM + kc;
      float4 a = *(const float4*)s;
      float4 v = *(const float4*)(s + 4);
      o[0] = f2b(a.x); o[1] = f2b(a.y); o[2] = f2b(a.z); o[3] = f2b(a.w);
      o[4] = f2b(v.x); o[5] = f2b(v.y); o[6] = f2b(v.z); o[7] = f2b(v.w);
    } else {
      #pragma unroll
      for (int j = 0; j < 8; ++j) o[j] = 0;
    }
    *(ushort8*)(wb + (size_t)idx * 8) = o;
    if (kc == 0) bias[p] = (c >= 0) ? bv[c] : 0.f;
  } else {
    int cb = blk - xblocks - wblocks;   // 0..CBLK-1
    if (tid < NBK) h[tid] = 0;
    __syncthreads();
    int start = cb * per, end = min(start + per, E);
    for (int i = start + tid; i < end; i += 256)
      atomicAdd(&h[bucket_of(ei[i], ei[E + i])], 1);
    __syncthreads();
    if (tid < NBK) counts[tid * CBLK + cb] = h[tid];
  }
}

// exclusive offsets: counts[k][b] -> base[k] + prefix_b  (in place)  [r8-proven]
__global__ void __launch_bounds__(1024) scan_k(int* __restrict__ counts)
{
  __shared__ int tot[NBK], base[NBK];
  const int tid = threadIdx.x, wv = tid >> 6, ln = tid & 63;
  for (int k = wv; k < NBK; k += 16) {
    int sum = 0;
    #pragma unroll
    for (int c = 0; c < CBLK / 64; ++c) sum += counts[k * CBLK + c * 64 + ln];
    #pragma unroll
    for (int off = 1; off < 64; off <<= 1) sum += __shfl_xor(sum, off);
    if (ln == 0) tot[k] = sum;
  }
  __syncthreads();
  if (tid == 0) {
    int run = 0;
    for (int k = 0; k < NBK; ++k) { base[k] = run; run += tot[k]; }
  }
  __syncthreads();
  for (int k = wv; k < NBK; k += 16) {
    int carry = base[k];
    #pragma unroll
    for (int c = 0; c < CBLK / 64; ++c) {
      int v = counts[k * CBLK + c * 64 + ln];
      int inc = v;
      #pragma unroll
      for (int off = 1; off < 64; off <<= 1) {
        int u = __shfl_up(inc, off);
        if (ln >= off) inc += u;
      }
      int last = __shfl(inc, 63);
      counts[k * CBLK + c * 64 + ln] = carry + inc - v;
      carry += last;
    }
  }
}

// Fused: GEMM blocks (r8/r12-proven structure) + scatter blocks in one dispatch.
__global__ void __launch_bounds__(256) gemm_scatter(
    const u16* __restrict__ xb, const u16* __restrict__ wb,
    const float* __restrict__ bias, u16* __restrict__ qkb,
    u16* __restrict__ tl, int M,
    const int* __restrict__ ei, const int* __restrict__ offs,
    uint2* __restrict__ sorted, int E, int per, int gemmBlocks, int mblocks)
{
  __shared__ u16 smem[GBM * EPITCH];
  const int tid = threadIdx.x;

  if (blockIdx.x >= gemmBlocks) {
    // ---- scatter branch ----
    int* cur = (int*)smem;
    const int blk = blockIdx.x - gemmBlocks;   // 0..CBLK-1
    if (tid < NBK) cur[tid] = offs[tid * CBLK + blk];
    __syncthreads();
    int start = blk * per, end = min(start + per, E);
    for (int i = start + tid; i < end; i += 256) {
      int s = ei[i], d = ei[E + i];
      int pos = atomicAdd(&cur[bucket_of(s, d)], 1);
      sorted[pos] = make_uint2(((unsigned)s << 16) | (unsigned)d, (unsigned)i);
    }
    return;
  }

  // ---- GEMM branch ----
  const int wave = tid >> 6, lane = tid & 63;
  const int l15 = lane & 15, lhi = lane >> 4;
  const int row0 = (blockIdx.x % mblocks) * GBM;
  const int p0   = (blockIdx.x / mblocks) * GBN;
  const int wr = (wave >> 1) * 64, wc = (wave & 1) * 64;

  f32x4 acc[4][4];
  #pragma unroll
  for (int m = 0; m < 4; ++m)
    #pragma unroll
    for (int n = 0; n < 4; ++n) acc[m][n] = (f32x4){0.f, 0.f, 0.f, 0.f};

#define STAGE(b, k0) do {                                                     \
    u16* As_ = smem + (b) * 8192;                                             \
    u16* Bs_ = As_ + 4096;                                                    \
    _Pragma("unroll")                                                         \
    for (int i_ = 0; i_ < 2; ++i_) {                                          \
      int f_ = wave * 128 + i_ * 64 + lane;                                   \
      int r_ = f_ >> 2, c_ = f_ & 3;                                          \
      const u16* gA = xb + (size_t)(row0 + r_) * K_DIM + (k0) + c_ * 8;       \
      __builtin_amdgcn_global_load_lds(                                       \
          (const __attribute__((address_space(1))) void*)gA,                  \
          (__attribute__((address_space(3))) void*)(As_ + (wave*128 + i_*64)*8), \
          16, 0, 0);                                                          \
      const u16* gB = wb + (size_t)(p0 + r_) * K_DIM + (k0) + c_ * 8;         \
      __builtin_amdgcn_global_load_lds(                                       \
          (const __attribute__((address_space(1))) void*)gB,                  \
          (__attribute__((address_space(3))) void*)(Bs_ + (wave*128 + i_*64)*8), \
          16, 0, 0);                                                          \
    }                                                                         \
  } while (0)

  STAGE(0, 0);
  asm volatile("s_waitcnt vmcnt(0)" ::: "memory");
  __syncthreads();

  #pragma unroll
  for (int t = 0; t < K_DIM / GBK; ++t) {
    if (t < K_DIM / GBK - 1) STAGE((t + 1) & 1, (t + 1) * GBK);
    const u16* As = smem + (t & 1) * 8192;
    const u16* Bs = As + 4096;
    short8 af[4], bf[4];
    #pragma unroll
    for (int m = 0; m < 4; ++m)
      af[m] = *(const short8*)(As + (size_t)(wr + m * 16 + l15) * GBK + lhi * 8);
    #pragma unroll
    for (int n = 0; n < 4; ++n)
      bf[n] = *(const short8*)(Bs + (size_t)(wc + n * 16 + l15) * GBK + lhi * 8);
    #pragma unroll
    for (int m = 0; m < 4; ++m)
      #pragma unroll
      for (int n = 0; n < 4; ++n)
        acc[m][n] = __builtin_amdgcn_mfma_f32_16x16x32_bf16(af[m], bf[n], acc[m][n], 0, 0, 0);
    if (t < K_DIM / GBK - 1) {
      asm volatile("s_waitcnt vmcnt(0)" ::: "memory");
      __syncthreads();
    }
  }
#undef STAGE

  __syncthreads();

  #pragma unroll
  for (int n = 0; n < 4; ++n) {
    int col = wc + n * 16 + l15;
    float bvv = bias[p0 + col];
    #pragma unroll
    for (int m = 0; m < 4; ++m) {
      #pragma unroll
      for (int r = 0; r < 4; ++r) {
        int row = wr + m * 16 + lhi * 4 + r;
        smem[row * EPITCH + col] = f2b(acc[m][n][r] + bvv);
      }
    }
  }
  __syncthreads();

  if (p0 < 512) {
    #pragma unroll
    for (int it = 0; it < 8; ++it) {
      int row  = wave * 32 + it * 4 + lhi;
      int grow = row0 + row;
      uint4 v = *(const uint4*)(smem + row * EPITCH + l15 * 8);
      if (grow < M)
        *(uint4*)(qkb + (size_t)grow * RQ + p0 + l15 * 8) = v;
    }
  } else {
    #pragma unroll
    for (int it = 0; it < 8; ++it) {
      int row  = wave * 32 + it * 4 + lhi;
      int grow = row0 + row;
      if (l15 == 0 && grow < M) {
        uint4 v = *(const uint4*)(smem + row * EPITCH);
        *(uint4*)(tl + (size_t)grow * 8) = v;
      }
    }
  }
}

// 16 edges per wave, 8 lanes per edge, 2-stage pipeline [r12-proven] at HIGH
// occupancy: launch_bounds(256,8) -> 32 waves/CU target (VGPR cap 64 > 44 used).
__global__ void __launch_bounds__(256, 8) edge_pass(
    const u16* __restrict__ qkb, const u16* __restrict__ tl,
    const uint2* __restrict__ sorted,
    u16* __restrict__ exh, float* __restrict__ denom, int E)
{
  const int tid  = threadIdx.x;
  const int wave = tid >> 6, lane = tid & 63;
  const int g = lane >> 3;
  const int l = lane & 7;

  const int nwg = gridDim.x;
  const int q8 = nwg >> 3, r8 = nwg & 7;
  const int xcd = blockIdx.x & 7, bix = blockIdx.x >> 3;
  const int swz = (xcd < r8) ? (xcd * (q8 + 1) + bix)
                             : (r8 * (q8 + 1) + (xcd - r8) * q8 + bix);

  const int s0 = swz * 64 + wave * 16 + g;
  const int s1 = s0 + 8;
  const bool v0 = s0 < E, v1 = s1 < E;
  uint2 r0 = sorted[v0 ? s0 : 0];
  uint2 r1 = sorted[v1 ? s1 : 0];
  const int src0 = r0.x >> 16, dst0 = r0.x & 0xffff;
  const int src1 = r1.x >> 16, dst1 = r1.x & 0xffff;

  const u16* q0p = qkb + (size_t)src0 * RQ + l * 32;
  const u16* k0p = qkb + (size_t)dst0 * RQ + 256 + l * 32;
  const u16* q1p = qkb + (size_t)src1 * RQ + l * 32;
  const u16* k1p = qkb + (size_t)dst1 * RQ + 256 + l * 32;

  uint4 qv0[4], kv0[4], qv1[4], kv1[4];
  #pragma unroll
  for (int c = 0; c < 4; ++c) {
    qv0[c] = *(const uint4*)(q0p + c * 8);
    kv0[c] = *(const uint4*)(k0p + c * 8);
  }
  #pragma unroll
  for (int c = 0; c < 4; ++c) {
    qv1[c] = *(const uint4*)(q1p + c * 8);
    kv1[c] = *(const uint4*)(k1p + c * 8);
  }
  int2 t0 = make_int2(0, 0), t1 = make_int2(0, 0);
  if (l < 2) {
    t0 = *(const int2*)(tl + (size_t)(l ? dst0 : src0) * 8 + (l ? 4 : 0));
    t1 = *(const int2*)(tl + (size_t)(l ? dst1 : src1) * 8 + (l ? 4 : 0));
  }

  const int h = l >> 1;
  const int idxA = ((g << 3) | (l & 1)) << 2;

#define EDGE_COMPUTE(qv, kv, ti, src_, e_, vld) do {                          \
    f32x2 a2 = {0.f, 0.f};                                                    \
    _Pragma("unroll")                                                         \
    for (int c = 0; c < 4; ++c) {                                             \
      const unsigned* qd = (const unsigned*)&qv[c];                           \
      const unsigned* kd = (const unsigned*)&kv[c];                           \
      _Pragma("unroll")                                                       \
      for (int j = 0; j < 4; ++j) {                                           \
        f32x2 qa = { asf(qd[j] << 16), asf(qd[j] & 0xffff0000u) };            \
        f32x2 ka = { asf(kd[j] << 16), asf(kd[j] & 0xffff0000u) };            \
        a2 += qa * ka;                                                        \
      }                                                                       \
    }                                                                         \
    float s = a2[0] + a2[1];                                                  \
    s += __shfl_xor(s, 1);                                                    \
    int w01 = __builtin_amdgcn_ds_bpermute(idxA, ti.x);                       \
    int w23 = __builtin_amdgcn_ds_bpermute(idxA, ti.y);                       \
    unsigned wsel = (h & 2) ? (unsigned)w23 : (unsigned)w01;                  \
    float tv = (h & 1) ? asf(wsel & 0xffff0000u) : asf(wsel << 16);           \
    float to = __shfl_xor(tv, 1);                                             \
    s = fmaf(tv, to, s);                                                      \
    float ev = __expf(s);                                                     \
    if ((vld) && (l & 1) == 0) {                                              \
      exh[(size_t)(e_) * 4 + h] = f2h(ev);                                    \
      unsafeAtomicAdd(&denom[(size_t)(src_) * 4 + h], ev);                    \
    }                                                                         \
  } while (0)

  EDGE_COMPUTE(qv0, kv0, t0, src0, r0.y, v0);
  EDGE_COMPUTE(qv1, kv1, t1, src1, r1.y, v1);
#undef EDGE_COMPUTE
}

__global__ void __launch_bounds__(256) finalize_k(
    const u16* __restrict__ exh, const float* __restrict__ denom,
    const int* __restrict__ ei, float* __restrict__ out, int E)
{
  int e = blockIdx.x * 256 + threadIdx.x;
  if (e >= E) return;
  int src = ei[e];
  ushort4 ev = *(const ushort4*)(exh + (size_t)e * 4);
  float4 dv = *(const float4*)(denom + (size_t)src * 4);
  out[e] = 0.25f * (h2f(ev.x) / dv.x + h2f(ev.y) / dv.y
                  + h2f(ev.z) / dv.z + h2f(ev.w) / dv.w);
}

extern "C" void kernel_launch(void* const* d_in, const int* in_sizes, int n_in,
                              void* d_out, int out_size, void* d_ws, size_t ws_size,
                              hipStream_t stream)
{
  const float* x  = (const float*)d_in[0];
  const int*   ei = (const int*)d_in[1];
  const float* W  = (const float*)d_in[2];
  const float* b  = (const float*)d_in[3];

  const int F = in_sizes[2] / in_sizes[3];   // 256
  const int M = in_sizes[0] / F;             // 50000
  const int E = in_sizes[1] / 2;             // 800000

  const int mblocks = (M + GBM - 1) / GBM;   // 391
  const int Mpad    = mblocks * GBM;         // 50048

  // ws: xb | wb | qkb | tl | bias | exh(u16) | denom | counts[NBK*CBLK] | sorted u2
  u16* xb  = (u16*)d_ws;
  u16* wb  = xb + (size_t)Mpad * K_DIM;
  u16* qkb = wb + (size_t)NPAD * K_DIM;
  u16* tl  = qkb + (size_t)M * RQ;
  float* bias  = (float*)(tl + (size_t)M * 8);
  u16*   exh   = (u16*)(bias + NPAD);
  float* denom = (float*)(exh + (size_t)E * 4);
  int*   counts = (int*)(denom + (size_t)M * 4);
  uint2* sorted = (uint2*)(counts + NBK * CBLK);

  const int xblocks = (Mpad * (K_DIM / 8) + 255) / 256;   // 6256
  const int wblocks = (NPAD * (K_DIM / 8) + 255) / 256;   // 80
  const int per     = (E + CBLK - 1) / CBLK;              // 3125

  hipMemsetAsync(denom, 0, (size_t)M * 4 * sizeof(float), stream);

  hipLaunchKernelGGL(prep, dim3(xblocks + wblocks + CBLK), dim3(256), 0,
                     stream, x, W, b, ei, xb, wb, bias, counts,
                     M, Mpad, E, per, xblocks, wblocks);

  hipLaunchKernelGGL(scan_k, dim3(1), dim3(1024), 0, stream, counts);

  const int gemmBlocks = mblocks * (NPAD / GBN);   // 1955
  hipLaunchKernelGGL(gemm_scatter, dim3(gemmBlocks + CBLK), dim3(256), 0, stream,
                     xb, wb, bias, qkb, tl, M,
                     ei, counts, sorted, E, per, gemmBlocks, mblocks);

  int eblocks = (E + 63) / 64;   // 64 sorted slots per block (16 per wave)
  hipLaunchKernelGGL(edge_pass, dim3(eblocks), dim3(256), 0, stream,
                     qkb, tl, sorted, exh, denom, E);

  hipLaunchKernelGGL(finalize_k, dim3((E + 255) / 256), dim3(256), 0, stream,
                     exh, denom, ei, (float*)d_out, E);
}

// Round 15
// 174.606 us; speedup vs baseline: 1.3426x; 1.3426x over previous
//
#include <hip/hip_runtime.h>
#include <hip/hip_bf16.h>

// N=50000, F=256, E=800000, H=4, P=65
#define K_DIM 256
#define RQ    512          // qkb row stride in bf16 elems (1024 B): [q 4x64 | k 4x64]
#define NPAD  640          // GEMM col padding: 5 panels of 128
#define GBM 128
#define GBN 128
#define GBK 32
#define EPITCH 152         // epilogue LDS pitch (elems)
#define NBK   104          // buckets: 8 regions x 13 src-sub (1024-node)  [r8-proven]
#define CBLK  256          // count/scatter blocks
#define SBAND 12512        // src band size (4 bands)
#define DBAND 25024        // dst band size (2 bands)

typedef unsigned short u16;
using short8  = __attribute__((ext_vector_type(8))) short;
using ushort8 = __attribute__((ext_vector_type(8))) unsigned short;
using f32x4   = __attribute__((ext_vector_type(4))) float;
using f32x2   = __attribute__((ext_vector_type(2))) float;

__device__ __forceinline__ float asf(unsigned u) {
  union { unsigned i; float f; } x; x.i = u; return x.f;
}
__device__ __forceinline__ u16 f2b(float f) {
  __hip_bfloat16 h = __float2bfloat16(f); return *(u16*)&h;
}
__device__ __forceinline__ u16 f2h(float f) { _Float16 h = (_Float16)f; return *(u16*)&h; }
__device__ __forceinline__ float h2f(u16 u) { _Float16 h = *(_Float16*)&u; return (float)h; }

// region-major bucket: (src_band*2 + dst_band)*13 + src_sub   [r8-proven]
__device__ __forceinline__ int bucket_of(int s, int d) {
  int sband = s / SBAND;                  // 0..3
  int dband = d / DBAND;                  // 0..1
  int ssub  = (s - sband * SBAND) >> 10;  // 0..12
  return ((sband << 1) | dband) * 13 + ssub;
}

// stored column p -> original W row c, or -1 for pad
__device__ __forceinline__ int map2(int p) {
  if (p < 256) return (p >> 6) * 130 + (p & 63);
  if (p < 512) { int q = p - 256; return (q >> 6) * 130 + 65 + (q & 63); }
  if (p < 516) return (p - 512) * 130 + 64;
  if (p < 520) return (p - 516) * 130 + 129;
  return -1;
}

// Fused: convert_x | convert_w(+bias) | bucket histogram  (denom zeroed by memset)
__global__ void __launch_bounds__(256) prep(
    const float* __restrict__ x, const float* __restrict__ W,
    const float* __restrict__ bv, const int* __restrict__ ei,
    u16* __restrict__ xb, u16* __restrict__ wb,
    float* __restrict__ bias, int* __restrict__ counts,
    int M, int Mpad, int E, int per, int xblocks, int wblocks)
{
  __shared__ int h[NBK];
  const int blk = blockIdx.x, tid = threadIdx.x;
  if (blk < xblocks) {
    int idx = blk * 256 + tid;
    int total = Mpad * (K_DIM / 8);
    if (idx >= total) return;
    int row = idx / (K_DIM / 8);
    ushort8 o;
    if (row < M) {
      const float* s = x + (size_t)idx * 8;
      float4 a = *(const float4*)s;
      float4 b = *(const float4*)(s + 4);
      o[0] = f2b(a.x); o[1] = f2b(a.y); o[2] = f2b(a.z); o[3] = f2b(a.w);
      o[4] = f2b(b.x); o[5] = f2b(b.y); o[6] = f2b(b.z); o[7] = f2b(b.w);
    } else {
      #pragma unroll
      for (int j = 0; j < 8; ++j) o[j] = 0;
    }
    *(ushort8*)(xb + (size_t)idx * 8) = o;
  } else if (blk < xblocks + wblocks) {
    int idx = (blk - xblocks) * 256 + tid;
    int total = NPAD * (K_DIM / 8);
    if (idx >= total) return;
    int p  = idx / (K_DIM / 8);
    int kc = (idx % (K_DIM / 8)) * 8;
    int c  = map2(p);
    ushort8 o;
    if (c >= 0) {
      const float* s = W + (size_t)c * K_DIM + kc;
      float4 a = *(const float4*)s;
      float4 v = *(const float4*)(s + 4);
      o[0] = f2b(a.x); o[1] = f2b(a.y); o[2] = f2b(a.z); o[3] = f2b(a.w);
      o[4] = f2b(v.x); o[5] = f2b(v.y); o[6] = f2b(v.z); o[7] = f2b(v.w);
    } else {
      #pragma unroll
      for (int j = 0; j < 8; ++j) o[j] = 0;
    }
    *(ushort8*)(wb + (size_t)idx * 8) = o;
    if (kc == 0) bias[p] = (c >= 0) ? bv[c] : 0.f;
  } else {
    int cb = blk - xblocks - wblocks;   // 0..CBLK-1
    if (tid < NBK) h[tid] = 0;
    __syncthreads();
    int start = cb * per, end = min(start + per, E);
    for (int i = start + tid; i < end; i += 256)
      atomicAdd(&h[bucket_of(ei[i], ei[E + i])], 1);
    __syncthreads();
    if (tid < NBK) counts[tid * CBLK + cb] = h[tid];
  }
}

// exclusive offsets: counts[k][b] -> base[k] + prefix_b  (in place)  [r8-proven]
__global__ void __launch_bounds__(1024) scan_k(int* __restrict__ counts)
{
  __shared__ int tot[NBK], base[NBK];
  const int tid = threadIdx.x, wv = tid >> 6, ln = tid & 63;
  for (int k = wv; k < NBK; k += 16) {
    int sum = 0;
    #pragma unroll
    for (int c = 0; c < CBLK / 64; ++c) sum += counts[k * CBLK + c * 64 + ln];
    #pragma unroll
    for (int off = 1; off < 64; off <<= 1) sum += __shfl_xor(sum, off);
    if (ln == 0) tot[k] = sum;
  }
  __syncthreads();
  if (tid == 0) {
    int run = 0;
    for (int k = 0; k < NBK; ++k) { base[k] = run; run += tot[k]; }
  }
  __syncthreads();
  for (int k = wv; k < NBK; k += 16) {
    int carry = base[k];
    #pragma unroll
    for (int c = 0; c < CBLK / 64; ++c) {
      int v = counts[k * CBLK + c * 64 + ln];
      int inc = v;
      #pragma unroll
      for (int off = 1; off < 64; off <<= 1) {
        int u = __shfl_up(inc, off);
        if (ln >= off) inc += u;
      }
      int last = __shfl(inc, 63);
      counts[k * CBLK + c * 64 + ln] = carry + inc - v;
      carry += last;
    }
  }
}

// Fused: GEMM blocks (r8/r12-proven structure) + scatter blocks in one dispatch.
__global__ void __launch_bounds__(256) gemm_scatter(
    const u16* __restrict__ xb, const u16* __restrict__ wb,
    const float* __restrict__ bias, u16* __restrict__ qkb,
    u16* __restrict__ tl, int M,
    const int* __restrict__ ei, const int* __restrict__ offs,
    uint2* __restrict__ sorted, int E, int per, int gemmBlocks, int mblocks)
{
  __shared__ u16 smem[GBM * EPITCH];
  const int tid = threadIdx.x;

  if (blockIdx.x >= gemmBlocks) {
    // ---- scatter branch ----
    int* cur = (int*)smem;
    const int blk = blockIdx.x - gemmBlocks;   // 0..CBLK-1
    if (tid < NBK) cur[tid] = offs[tid * CBLK + blk];
    __syncthreads();
    int start = blk * per, end = min(start + per, E);
    for (int i = start + tid; i < end; i += 256) {
      int s = ei[i], d = ei[E + i];
      int pos = atomicAdd(&cur[bucket_of(s, d)], 1);
      sorted[pos] = make_uint2(((unsigned)s << 16) | (unsigned)d, (unsigned)i);
    }
    return;
  }

  // ---- GEMM branch ----
  const int wave = tid >> 6, lane = tid & 63;
  const int l15 = lane & 15, lhi = lane >> 4;
  const int row0 = (blockIdx.x % mblocks) * GBM;
  const int p0   = (blockIdx.x / mblocks) * GBN;
  const int wr = (wave >> 1) * 64, wc = (wave & 1) * 64;

  f32x4 acc[4][4];
  #pragma unroll
  for (int m = 0; m < 4; ++m)
    #pragma unroll
    for (int n = 0; n < 4; ++n) acc[m][n] = (f32x4){0.f, 0.f, 0.f, 0.f};

#define STAGE(b, k0) do {                                                     \
    u16* As_ = smem + (b) * 8192;                                             \
    u16* Bs_ = As_ + 4096;                                                    \
    _Pragma("unroll")                                                         \
    for (int i_ = 0; i_ < 2; ++i_) {                                          \
      int f_ = wave * 128 + i_ * 64 + lane;                                   \
      int r_ = f_ >> 2, c_ = f_ & 3;                                          \
      const u16* gA = xb + (size_t)(row0 + r_) * K_DIM + (k0) + c_ * 8;       \
      __builtin_amdgcn_global_load_lds(                                       \
          (const __attribute__((address_space(1))) void*)gA,                  \
          (__attribute__((address_space(3))) void*)(As_ + (wave*128 + i_*64)*8), \
          16, 0, 0);                                                          \
      const u16* gB = wb + (size_t)(p0 + r_) * K_DIM + (k0) + c_ * 8;         \
      __builtin_amdgcn_global_load_lds(                                       \
          (const __attribute__((address_space(1))) void*)gB,                  \
          (__attribute__((address_space(3))) void*)(Bs_ + (wave*128 + i_*64)*8), \
          16, 0, 0);                                                          \
    }                                                                         \
  } while (0)

  STAGE(0, 0);
  asm volatile("s_waitcnt vmcnt(0)" ::: "memory");
  __syncthreads();

  #pragma unroll
  for (int t = 0; t < K_DIM / GBK; ++t) {
    if (t < K_DIM / GBK - 1) STAGE((t + 1) & 1, (t + 1) * GBK);
    const u16* As = smem + (t & 1) * 8192;
    const u16* Bs = As + 4096;
    short8 af[4], bf[4];
    #pragma unroll
    for (int m = 0; m < 4; ++m)
      af[m] = *(const short8*)(As + (size_t)(wr + m * 16 + l15) * GBK + lhi * 8);
    #pragma unroll
    for (int n = 0; n < 4; ++n)
      bf[n] = *(const short8*)(Bs + (size_t)(wc + n * 16 + l15) * GBK + lhi * 8);
    #pragma unroll
    for (int m = 0; m < 4; ++m)
      #pragma unroll
      for (int n = 0; n < 4; ++n)
        acc[m][n] = __builtin_amdgcn_mfma_f32_16x16x32_bf16(af[m], bf[n], acc[m][n], 0, 0, 0);
    if (t < K_DIM / GBK - 1) {
      asm volatile("s_waitcnt vmcnt(0)" ::: "memory");
      __syncthreads();
    }
  }
#undef STAGE

  __syncthreads();

  #pragma unroll
  for (int n = 0; n < 4; ++n) {
    int col = wc + n * 16 + l15;
    float bvv = bias[p0 + col];
    #pragma unroll
    for (int m = 0; m < 4; ++m) {
      #pragma unroll
      for (int r = 0; r < 4; ++r) {
        int row = wr + m * 16 + lhi * 4 + r;
        smem[row * EPITCH + col] = f2b(acc[m][n][r] + bvv);
      }
    }
  }
  __syncthreads();

  if (p0 < 512) {
    #pragma unroll
    for (int it = 0; it < 8; ++it) {
      int row  = wave * 32 + it * 4 + lhi;
      int grow = row0 + row;
      uint4 v = *(const uint4*)(smem + row * EPITCH + l15 * 8);
      if (grow < M)
        *(uint4*)(qkb + (size_t)grow * RQ + p0 + l15 * 8) = v;
    }
  } else {
    #pragma unroll
    for (int it = 0; it < 8; ++it) {
      int row  = wave * 32 + it * 4 + lhi;
      int grow = row0 + row;
      if (l15 == 0 && grow < M) {
        uint4 v = *(const uint4*)(smem + row * EPITCH);
        *(uint4*)(tl + (size_t)grow * 8) = v;
      }
    }
  }
}

// 16 edges per wave, 8 lanes per edge, 2-stage pipeline [r12-proven].
// launch_bounds(256,6): VGPR cap 84 (> 44 used at r12, no spill) while raising
// the residency ceiling 16 -> 24 waves/CU. (256,8) spilled: cap 64 -> 32 VGPR
// + 212 MB scratch traffic, dur 156 us. Occupancy bought with spills is a loss.
__global__ void __launch_bounds__(256, 6) edge_pass(
    const u16* __restrict__ qkb, const u16* __restrict__ tl,
    const uint2* __restrict__ sorted,
    u16* __restrict__ exh, float* __restrict__ denom, int E)
{
  const int tid  = threadIdx.x;
  const int wave = tid >> 6, lane = tid & 63;
  const int g = lane >> 3;
  const int l = lane & 7;

  const int nwg = gridDim.x;
  const int q8 = nwg >> 3, r8 = nwg & 7;
  const int xcd = blockIdx.x & 7, bix = blockIdx.x >> 3;
  const int swz = (xcd < r8) ? (xcd * (q8 + 1) + bix)
                             : (r8 * (q8 + 1) + (xcd - r8) * q8 + bix);

  const int s0 = swz * 64 + wave * 16 + g;
  const int s1 = s0 + 8;
  const bool v0 = s0 < E, v1 = s1 < E;
  uint2 r0 = sorted[v0 ? s0 : 0];
  uint2 r1 = sorted[v1 ? s1 : 0];
  const int src0 = r0.x >> 16, dst0 = r0.x & 0xffff;
  const int src1 = r1.x >> 16, dst1 = r1.x & 0xffff;

  const u16* q0p = qkb + (size_t)src0 * RQ + l * 32;
  const u16* k0p = qkb + (size_t)dst0 * RQ + 256 + l * 32;
  const u16* q1p = qkb + (size_t)src1 * RQ + l * 32;
  const u16* k1p = qkb + (size_t)dst1 * RQ + 256 + l * 32;

  uint4 qv0[4], kv0[4], qv1[4], kv1[4];
  #pragma unroll
  for (int c = 0; c < 4; ++c) {
    qv0[c] = *(const uint4*)(q0p + c * 8);
    kv0[c] = *(const uint4*)(k0p + c * 8);
  }
  #pragma unroll
  for (int c = 0; c < 4; ++c) {
    qv1[c] = *(const uint4*)(q1p + c * 8);
    kv1[c] = *(const uint4*)(k1p + c * 8);
  }
  int2 t0 = make_int2(0, 0), t1 = make_int2(0, 0);
  if (l < 2) {
    t0 = *(const int2*)(tl + (size_t)(l ? dst0 : src0) * 8 + (l ? 4 : 0));
    t1 = *(const int2*)(tl + (size_t)(l ? dst1 : src1) * 8 + (l ? 4 : 0));
  }

  const int h = l >> 1;
  const int idxA = ((g << 3) | (l & 1)) << 2;

#define EDGE_COMPUTE(qv, kv, ti, src_, e_, vld) do {                          \
    f32x2 a2 = {0.f, 0.f};                                                    \
    _Pragma("unroll")                                                         \
    for (int c = 0; c < 4; ++c) {                                             \
      const unsigned* qd = (const unsigned*)&qv[c];                           \
      const unsigned* kd = (const unsigned*)&kv[c];                           \
      _Pragma("unroll")                                                       \
      for (int j = 0; j < 4; ++j) {                                           \
        f32x2 qa = { asf(qd[j] << 16), asf(qd[j] & 0xffff0000u) };            \
        f32x2 ka = { asf(kd[j] << 16), asf(kd[j] & 0xffff0000u) };            \
        a2 += qa * ka;                                                        \
      }                                                                       \
    }                                                                         \
    float s = a2[0] + a2[1];                                                  \
    s += __shfl_xor(s, 1);                                                    \
    int w01 = __builtin_amdgcn_ds_bpermute(idxA, ti.x);                       \
    int w23 = __builtin_amdgcn_ds_bpermute(idxA, ti.y);                       \
    unsigned wsel = (h & 2) ? (unsigned)w23 : (unsigned)w01;                  \
    float tv = (h & 1) ? asf(wsel & 0xffff0000u) : asf(wsel << 16);           \
    float to = __shfl_xor(tv, 1);                                             \
    s = fmaf(tv, to, s);                                                      \
    float ev = __expf(s);                                                     \
    if ((vld) && (l & 1) == 0) {                                              \
      exh[(size_t)(e_) * 4 + h] = f2h(ev);                                    \
      unsafeAtomicAdd(&denom[(size_t)(src_) * 4 + h], ev);                    \
    }                                                                         \
  } while (0)

  EDGE_COMPUTE(qv0, kv0, t0, src0, r0.y, v0);
  EDGE_COMPUTE(qv1, kv1, t1, src1, r1.y, v1);
#undef EDGE_COMPUTE
}

__global__ void __launch_bounds__(256) finalize_k(
    const u16* __restrict__ exh, const float* __restrict__ denom,
    const int* __restrict__ ei, float* __restrict__ out, int E)
{
  int e = blockIdx.x * 256 + threadIdx.x;
  if (e >= E) return;
  int src = ei[e];
  ushort4 ev = *(const ushort4*)(exh + (size_t)e * 4);
  float4 dv = *(const float4*)(denom + (size_t)src * 4);
  out[e] = 0.25f * (h2f(ev.x) / dv.x + h2f(ev.y) / dv.y
                  + h2f(ev.z) / dv.z + h2f(ev.w) / dv.w);
}

extern "C" void kernel_launch(void* const* d_in, const int* in_sizes, int n_in,
                              void* d_out, int out_size, void* d_ws, size_t ws_size,
                              hipStream_t stream)
{
  const float* x  = (const float*)d_in[0];
  const int*   ei = (const int*)d_in[1];
  const float* W  = (const float*)d_in[2];
  const float* b  = (const float*)d_in[3];

  const int F = in_sizes[2] / in_sizes[3];   // 256
  const int M = in_sizes[0] / F;             // 50000
  const int E = in_sizes[1] / 2;             // 800000

  const int mblocks = (M + GBM - 1) / GBM;   // 391
  const int Mpad    = mblocks * GBM;         // 50048

  // ws: xb | wb | qkb | tl | bias | exh(u16) | denom | counts[NBK*CBLK] | sorted u2
  u16* xb  = (u16*)d_ws;
  u16* wb  = xb + (size_t)Mpad * K_DIM;
  u16* qkb = wb + (size_t)NPAD * K_DIM;
  u16* tl  = qkb + (size_t)M * RQ;
  float* bias  = (float*)(tl + (size_t)M * 8);
  u16*   exh   = (u16*)(bias + NPAD);
  float* denom = (float*)(exh + (size_t)E * 4);
  int*   counts = (int*)(denom + (size_t)M * 4);
  uint2* sorted = (uint2*)(counts + NBK * CBLK);

  const int xblocks = (Mpad * (K_DIM / 8) + 255) / 256;   // 6256
  const int wblocks = (NPAD * (K_DIM / 8) + 255) / 256;   // 80
  const int per     = (E + CBLK - 1) / CBLK;              // 3125

  hipMemsetAsync(denom, 0, (size_t)M * 4 * sizeof(float), stream);

  hipLaunchKernelGGL(prep, dim3(xblocks + wblocks + CBLK), dim3(256), 0,
                     stream, x, W, b, ei, xb, wb, bias, counts,
                     M, Mpad, E, per, xblocks, wblocks);

  hipLaunchKernelGGL(scan_k, dim3(1), dim3(1024), 0, stream, counts);

  const int gemmBlocks = mblocks * (NPAD / GBN);   // 1955
  hipLaunchKernelGGL(gemm_scatter, dim3(gemmBlocks + CBLK), dim3(256), 0, stream,
                     xb, wb, bias, qkb, tl, M,
                     ei, counts, sorted, E, per, gemmBlocks, mblocks);

  int eblocks = (E + 63) / 64;   // 64 sorted slots per block (16 per wave)
  hipLaunchKernelGGL(edge_pass, dim3(eblocks), dim3(256), 0, stream,
                     qkb, tl, sorted, exh, denom, E);

  hipLaunchKernelGGL(finalize_k, dim3((E + 255) / 256), dim3(256), 0, stream,
                     exh, denom, ei, (float*)d_out, E);
}

// Round 16
// 161.005 us; speedup vs baseline: 1.4561x; 1.0845x over previous
//
#include <hip/hip_runtime.h>
#include <hip/hip_bf16.h>

// N=50000, F=256, E=800000, H=4, P=65
#define K_DIM 256
#define RQ    512          // qkb row stride in bf16 elems (1024 B): [q 4x64 | k 4x64]
#define NPAD  640          // GEMM col padding: 5 panels of 128
#define NPAN  5
#define GBM 128
#define GBN 128
#define GBK 32
#define EPITCH 152         // epilogue LDS pitch (elems)
#define NBK   104          // buckets: 8 regions x 13 src-sub (1024-node)  [r8-proven]
#define CBLK  256          // count/scatter blocks
#define SBAND 12512        // src band size (4 bands)
#define DBAND 25024        // dst band size (2 bands)

typedef unsigned short u16;
using short8  = __attribute__((ext_vector_type(8))) short;
using ushort8 = __attribute__((ext_vector_type(8))) unsigned short;
using f32x4   = __attribute__((ext_vector_type(4))) float;
using f32x2   = __attribute__((ext_vector_type(2))) float;

__device__ __forceinline__ float asf(unsigned u) {
  union { unsigned i; float f; } x; x.i = u; return x.f;
}
__device__ __forceinline__ u16 f2b(float f) {
  __hip_bfloat16 h = __float2bfloat16(f); return *(u16*)&h;
}
__device__ __forceinline__ u16 f2h(float f) { _Float16 h = (_Float16)f; return *(u16*)&h; }
__device__ __forceinline__ float h2f(u16 u) { _Float16 h = *(_Float16*)&u; return (float)h; }

// region-major bucket: (src_band*2 + dst_band)*13 + src_sub   [r8-proven]
__device__ __forceinline__ int bucket_of(int s, int d) {
  int sband = s / SBAND;                  // 0..3
  int dband = d / DBAND;                  // 0..1
  int ssub  = (s - sband * SBAND) >> 10;  // 0..12
  return ((sband << 1) | dband) * 13 + ssub;
}

// stored column p -> original W row c, or -1 for pad
__device__ __forceinline__ int map2(int p) {
  if (p < 256) return (p >> 6) * 130 + (p & 63);
  if (p < 512) { int q = p - 256; return (q >> 6) * 130 + 65 + (q & 63); }
  if (p < 516) return (p - 512) * 130 + 64;
  if (p < 520) return (p - 516) * 130 + 129;
  return -1;
}

// Fused: convert_x | convert_w(+bias) | bucket histogram  (denom zeroed by memset)
__global__ void __launch_bounds__(256) prep(
    const float* __restrict__ x, const float* __restrict__ W,
    const float* __restrict__ bv, const int* __restrict__ ei,
    u16* __restrict__ xb, u16* __restrict__ wb,
    float* __restrict__ bias, int* __restrict__ counts,
    int M, int Mpad, int E, int per, int xblocks, int wblocks)
{
  __shared__ int h[NBK];
  const int blk = blockIdx.x, tid = threadIdx.x;
  if (blk < xblocks) {
    int idx = blk * 256 + tid;
    int total = Mpad * (K_DIM / 8);
    if (idx >= total) return;
    int row = idx / (K_DIM / 8);
    ushort8 o;
    if (row < M) {
      const float* s = x + (size_t)idx * 8;
      float4 a = *(const float4*)s;
      float4 b = *(const float4*)(s + 4);
      o[0] = f2b(a.x); o[1] = f2b(a.y); o[2] = f2b(a.z); o[3] = f2b(a.w);
      o[4] = f2b(b.x); o[5] = f2b(b.y); o[6] = f2b(b.z); o[7] = f2b(b.w);
    } else {
      #pragma unroll
      for (int j = 0; j < 8; ++j) o[j] = 0;
    }
    *(ushort8*)(xb + (size_t)idx * 8) = o;
  } else if (blk < xblocks + wblocks) {
    int idx = (blk - xblocks) * 256 + tid;
    int total = NPAD * (K_DIM / 8);
    if (idx >= total) return;
    int p  = idx / (K_DIM / 8);
    int kc = (idx % (K_DIM / 8)) * 8;
    int c  = map2(p);
    ushort8 o;
    if (c >= 0) {
      const float* s = W + (size_t)c * K_DIM + kc;
      float4 a = *(const float4*)s;
      float4 v = *(const float4*)(s + 4);
      o[0] = f2b(a.x); o[1] = f2b(a.y); o[2] = f2b(a.z); o[3] = f2b(a.w);
      o[4] = f2b(v.x); o[5] = f2b(v.y); o[6] = f2b(v.z); o[7] = f2b(v.w);
    } else {
      #pragma unroll
      for (int j = 0; j < 8; ++j) o[j] = 0;
    }
    *(ushort8*)(wb + (size_t)idx * 8) = o;
    if (kc == 0) bias[p] = (c >= 0) ? bv[c] : 0.f;
  } else {
    int cb = blk - xblocks - wblocks;   // 0..CBLK-1
    if (tid < NBK) h[tid] = 0;
    __syncthreads();
    int start = cb * per, end = min(start + per, E);
    for (int i = start + tid; i < end; i += 256)
      atomicAdd(&h[bucket_of(ei[i], ei[E + i])], 1);
    __syncthreads();
    if (tid < NBK) counts[tid * CBLK + cb] = h[tid];
  }
}

// exclusive offsets: counts[k][b] -> base[k] + prefix_b  (in place)  [r8-proven]
__global__ void __launch_bounds__(1024) scan_k(int* __restrict__ counts)
{
  __shared__ int tot[NBK], base[NBK];
  const int tid = threadIdx.x, wv = tid >> 6, ln = tid & 63;
  for (int k = wv; k < NBK; k += 16) {
    int sum = 0;
    #pragma unroll
    for (int c = 0; c < CBLK / 64; ++c) sum += counts[k * CBLK + c * 64 + ln];
    #pragma unroll
    for (int off = 1; off < 64; off <<= 1) sum += __shfl_xor(sum, off);
    if (ln == 0) tot[k] = sum;
  }
  __syncthreads();
  if (tid == 0) {
    int run = 0;
    for (int k = 0; k < NBK; ++k) { base[k] = run; run += tot[k]; }
  }
  __syncthreads();
  for (int k = wv; k < NBK; k += 16) {
    int carry = base[k];
    #pragma unroll
    for (int c = 0; c < CBLK / 64; ++c) {
      int v = counts[k * CBLK + c * 64 + ln];
      int inc = v;
      #pragma unroll
      for (int off = 1; off < 64; off <<= 1) {
        int u = __shfl_up(inc, off);
        if (ln >= off) inc += u;
      }
      int last = __shfl(inc, 63);
      counts[k * CBLK + c * 64 + ln] = carry + inc - v;
      carry += last;
    }
  }
}

// Fused: GEMM blocks (r8/r12-proven inner structure) + scatter blocks.
// GEMM block mapping is M-major panel-minor with bijective XCD chunking:
// each XCD's contiguous chunk covers ~49 M-tiles x all 5 panels, so the
// A-chunk (3.2 MB < 4 MB L2) is fetched once and reused for all panels.
__global__ void __launch_bounds__(256) gemm_scatter(
    const u16* __restrict__ xb, const u16* __restrict__ wb,
    const float* __restrict__ bias, u16* __restrict__ qkb,
    u16* __restrict__ tl, int M,
    const int* __restrict__ ei, const int* __restrict__ offs,
    uint2* __restrict__ sorted, int E, int per, int gemmBlocks, int mblocks)
{
  __shared__ u16 smem[GBM * EPITCH];
  const int tid = threadIdx.x;

  if (blockIdx.x >= gemmBlocks) {
    // ---- scatter branch ----
    int* cur = (int*)smem;
    const int blk = blockIdx.x - gemmBlocks;   // 0..CBLK-1
    if (tid < NBK) cur[tid] = offs[tid * CBLK + blk];
    __syncthreads();
    int start = blk * per, end = min(start + per, E);
    for (int i = start + tid; i < end; i += 256) {
      int s = ei[i], d = ei[E + i];
      int pos = atomicAdd(&cur[bucket_of(s, d)], 1);
      sorted[pos] = make_uint2(((unsigned)s << 16) | (unsigned)d, (unsigned)i);
    }
    return;
  }

  // ---- GEMM branch ----
  const int wave = tid >> 6, lane = tid & 63;
  const int l15 = lane & 15, lhi = lane >> 4;
  // bijective XCD swizzle over gemm blocks (m204)
  const int nb = gemmBlocks;
  const int q8 = nb >> 3, r8 = nb & 7;
  const int xcd = blockIdx.x & 7, bix = blockIdx.x >> 3;
  const int swz = (xcd < r8) ? (xcd * (q8 + 1) + bix)
                             : (r8 * (q8 + 1) + (xcd - r8) * q8 + bix);
  const int row0 = (swz / NPAN) * GBM;       // M-major
  const int p0   = (swz % NPAN) * GBN;       // panel-minor
  const int wr = (wave >> 1) * 64, wc = (wave & 1) * 64;

  f32x4 acc[4][4];
  #pragma unroll
  for (int m = 0; m < 4; ++m)
    #pragma unroll
    for (int n = 0; n < 4; ++n) acc[m][n] = (f32x4){0.f, 0.f, 0.f, 0.f};

#define STAGE(b, k0) do {                                                     \
    u16* As_ = smem + (b) * 8192;                                             \
    u16* Bs_ = As_ + 4096;                                                    \
    _Pragma("unroll")                                                         \
    for (int i_ = 0; i_ < 2; ++i_) {                                          \
      int f_ = wave * 128 + i_ * 64 + lane;                                   \
      int r_ = f_ >> 2, c_ = f_ & 3;                                          \
      const u16* gA = xb + (size_t)(row0 + r_) * K_DIM + (k0) + c_ * 8;       \
      __builtin_amdgcn_global_load_lds(                                       \
          (const __attribute__((address_space(1))) void*)gA,                  \
          (__attribute__((address_space(3))) void*)(As_ + (wave*128 + i_*64)*8), \
          16, 0, 0);                                                          \
      const u16* gB = wb + (size_t)(p0 + r_) * K_DIM + (k0) + c_ * 8;         \
      __builtin_amdgcn_global_load_lds(                                       \
          (const __attribute__((address_space(1))) void*)gB,                  \
          (__attribute__((address_space(3))) void*)(Bs_ + (wave*128 + i_*64)*8), \
          16, 0, 0);                                                          \
    }                                                                         \
  } while (0)

  STAGE(0, 0);
  asm volatile("s_waitcnt vmcnt(0)" ::: "memory");
  __syncthreads();

  #pragma unroll
  for (int t = 0; t < K_DIM / GBK; ++t) {
    if (t < K_DIM / GBK - 1) STAGE((t + 1) & 1, (t + 1) * GBK);
    const u16* As = smem + (t & 1) * 8192;
    const u16* Bs = As + 4096;
    short8 af[4], bf[4];
    #pragma unroll
    for (int m = 0; m < 4; ++m)
      af[m] = *(const short8*)(As + (size_t)(wr + m * 16 + l15) * GBK + lhi * 8);
    #pragma unroll
    for (int n = 0; n < 4; ++n)
      bf[n] = *(const short8*)(Bs + (size_t)(wc + n * 16 + l15) * GBK + lhi * 8);
    #pragma unroll
    for (int m = 0; m < 4; ++m)
      #pragma unroll
      for (int n = 0; n < 4; ++n)
        acc[m][n] = __builtin_amdgcn_mfma_f32_16x16x32_bf16(af[m], bf[n], acc[m][n], 0, 0, 0);
    if (t < K_DIM / GBK - 1) {
      asm volatile("s_waitcnt vmcnt(0)" ::: "memory");
      __syncthreads();
    }
  }
#undef STAGE

  __syncthreads();

  #pragma unroll
  for (int n = 0; n < 4; ++n) {
    int col = wc + n * 16 + l15;
    float bvv = bias[p0 + col];
    #pragma unroll
    for (int m = 0; m < 4; ++m) {
      #pragma unroll
      for (int r = 0; r < 4; ++r) {
        int row = wr + m * 16 + lhi * 4 + r;
        smem[row * EPITCH + col] = f2b(acc[m][n][r] + bvv);
      }
    }
  }
  __syncthreads();

  if (p0 < 512) {
    #pragma unroll
    for (int it = 0; it < 8; ++it) {
      int row  = wave * 32 + it * 4 + lhi;
      int grow = row0 + row;
      uint4 v = *(const uint4*)(smem + row * EPITCH + l15 * 8);
      if (grow < M)
        *(uint4*)(qkb + (size_t)grow * RQ + p0 + l15 * 8) = v;
    }
  } else {
    #pragma unroll
    for (int it = 0; it < 8; ++it) {
      int row  = wave * 32 + it * 4 + lhi;
      int grow = row0 + row;
      if (l15 == 0 && grow < M) {
        uint4 v = *(const uint4*)(smem + row * EPITCH);
        *(uint4*)(tl + (size_t)grow * 8) = v;
      }
    }
  }
}

// 16 edges per wave, 8 lanes per edge, 2-stage pipeline. r12-EXACT config:
// launch_bounds(256,4) -> 44 VGPR, no spill, 83.6 us. (256,6) and (256,8)
// both spilled (77/262 MB scratch writes) and regressed — do not retune.
__global__ void __launch_bounds__(256, 4) edge_pass(
    const u16* __restrict__ qkb, const u16* __restrict__ tl,
    const uint2* __restrict__ sorted,
    u16* __restrict__ exh, float* __restrict__ denom, int E)
{
  const int tid  = threadIdx.x;
  const int wave = tid >> 6, lane = tid & 63;
  const int g = lane >> 3;
  const int l = lane & 7;

  const int nwg = gridDim.x;
  const int q8 = nwg >> 3, r8 = nwg & 7;
  const int xcd = blockIdx.x & 7, bix = blockIdx.x >> 3;
  const int swz = (xcd < r8) ? (xcd * (q8 + 1) + bix)
                             : (r8 * (q8 + 1) + (xcd - r8) * q8 + bix);

  const int s0 = swz * 64 + wave * 16 + g;
  const int s1 = s0 + 8;
  const bool v0 = s0 < E, v1 = s1 < E;
  uint2 r0 = sorted[v0 ? s0 : 0];
  uint2 r1 = sorted[v1 ? s1 : 0];
  const int src0 = r0.x >> 16, dst0 = r0.x & 0xffff;
  const int src1 = r1.x >> 16, dst1 = r1.x & 0xffff;

  const u16* q0p = qkb + (size_t)src0 * RQ + l * 32;
  const u16* k0p = qkb + (size_t)dst0 * RQ + 256 + l * 32;
  const u16* q1p = qkb + (size_t)src1 * RQ + l * 32;
  const u16* k1p = qkb + (size_t)dst1 * RQ + 256 + l * 32;

  uint4 qv0[4], kv0[4], qv1[4], kv1[4];
  #pragma unroll
  for (int c = 0; c < 4; ++c) {
    qv0[c] = *(const uint4*)(q0p + c * 8);
    kv0[c] = *(const uint4*)(k0p + c * 8);
  }
  #pragma unroll
  for (int c = 0; c < 4; ++c) {
    qv1[c] = *(const uint4*)(q1p + c * 8);
    kv1[c] = *(const uint4*)(k1p + c * 8);
  }
  int2 t0 = make_int2(0, 0), t1 = make_int2(0, 0);
  if (l < 2) {
    t0 = *(const int2*)(tl + (size_t)(l ? dst0 : src0) * 8 + (l ? 4 : 0));
    t1 = *(const int2*)(tl + (size_t)(l ? dst1 : src1) * 8 + (l ? 4 : 0));
  }

  const int h = l >> 1;
  const int idxA = ((g << 3) | (l & 1)) << 2;

#define EDGE_COMPUTE(qv, kv, ti, src_, e_, vld) do {                          \
    f32x2 a2 = {0.f, 0.f};                                                    \
    _Pragma("unroll")                                                         \
    for (int c = 0; c < 4; ++c) {                                             \
      const unsigned* qd = (const unsigned*)&qv[c];                           \
      const unsigned* kd = (const unsigned*)&kv[c];                           \
      _Pragma("unroll")                                                       \
      for (int j = 0; j < 4; ++j) {                                           \
        f32x2 qa = { asf(qd[j] << 16), asf(qd[j] & 0xffff0000u) };            \
        f32x2 ka = { asf(kd[j] << 16), asf(kd[j] & 0xffff0000u) };            \
        a2 += qa * ka;                                                        \
      }                                                                       \
    }                                                                         \
    float s = a2[0] + a2[1];                                                  \
    s += __shfl_xor(s, 1);                                                    \
    int w01 = __builtin_amdgcn_ds_bpermute(idxA, ti.x);                       \
    int w23 = __builtin_amdgcn_ds_bpermute(idxA, ti.y);                       \
    unsigned wsel = (h & 2) ? (unsigned)w23 : (unsigned)w01;                  \
    float tv = (h & 1) ? asf(wsel & 0xffff0000u) : asf(wsel << 16);           \
    float to = __shfl_xor(tv, 1);                                             \
    s = fmaf(tv, to, s);                                                      \
    float ev = __expf(s);                                                     \
    if ((vld) && (l & 1) == 0) {                                              \
      exh[(size_t)(e_) * 4 + h] = f2h(ev);                                    \
      unsafeAtomicAdd(&denom[(size_t)(src_) * 4 + h], ev);                    \
    }                                                                         \
  } while (0)

  EDGE_COMPUTE(qv0, kv0, t0, src0, r0.y, v0);
  EDGE_COMPUTE(qv1, kv1, t1, src1, r1.y, v1);
#undef EDGE_COMPUTE
}

__global__ void __launch_bounds__(256) finalize_k(
    const u16* __restrict__ exh, const float* __restrict__ denom,
    const int* __restrict__ ei, float* __restrict__ out, int E)
{
  int e = blockIdx.x * 256 + threadIdx.x;
  if (e >= E) return;
  int src = ei[e];
  ushort4 ev = *(const ushort4*)(exh + (size_t)e * 4);
  float4 dv = *(const float4*)(denom + (size_t)src * 4);
  out[e] = 0.25f * (h2f(ev.x) / dv.x + h2f(ev.y) / dv.y
                  + h2f(ev.z) / dv.z + h2f(ev.w) / dv.w);
}

extern "C" void kernel_launch(void* const* d_in, const int* in_sizes, int n_in,
                              void* d_out, int out_size, void* d_ws, size_t ws_size,
                              hipStream_t stream)
{
  const float* x  = (const float*)d_in[0];
  const int*   ei = (const int*)d_in[1];
  const float* W  = (const float*)d_in[2];
  const float* b  = (const float*)d_in[3];

  const int F = in_sizes[2] / in_sizes[3];   // 256
  const int M = in_sizes[0] / F;             // 50000
  const int E = in_sizes[1] / 2;             // 800000

  const int mblocks = (M + GBM - 1) / GBM;   // 391
  const int Mpad    = mblocks * GBM;         // 50048

  // ws: xb | wb | qkb | tl | bias | exh(u16) | denom | counts[NBK*CBLK] | sorted u2
  u16* xb  = (u16*)d_ws;
  u16* wb  = xb + (size_t)Mpad * K_DIM;
  u16* qkb = wb + (size_t)NPAD * K_DIM;
  u16* tl  = qkb + (size_t)M * RQ;
  float* bias  = (float*)(tl + (size_t)M * 8);
  u16*   exh   = (u16*)(bias + NPAD);
  float* denom = (float*)(exh + (size_t)E * 4);
  int*   counts = (int*)(denom + (size_t)M * 4);
  uint2* sorted = (uint2*)(counts + NBK * CBLK);

  const int xblocks = (Mpad * (K_DIM / 8) + 255) / 256;   // 6256
  const int wblocks = (NPAD * (K_DIM / 8) + 255) / 256;   // 80
  const int per     = (E + CBLK - 1) / CBLK;              // 3125

  hipMemsetAsync(denom, 0, (size_t)M * 4 * sizeof(float), stream);

  hipLaunchKernelGGL(prep, dim3(xblocks + wblocks + CBLK), dim3(256), 0,
                     stream, x, W, b, ei, xb, wb, bias, counts,
                     M, Mpad, E, per, xblocks, wblocks);

  hipLaunchKernelGGL(scan_k, dim3(1), dim3(1024), 0, stream, counts);

  const int gemmBlocks = mblocks * NPAN;   // 1955
  hipLaunchKernelGGL(gemm_scatter, dim3(gemmBlocks + CBLK), dim3(256), 0, stream,
                     xb, wb, bias, qkb, tl, M,
                     ei, counts, sorted, E, per, gemmBlocks, mblocks);

  int eblocks = (E + 63) / 64;   // 64 sorted slots per block (16 per wave)
  hipLaunchKernelGGL(edge_pass, dim3(eblocks), dim3(256), 0, stream,
                     qkb, tl, sorted, exh, denom, E);

  hipLaunchKernelGGL(finalize_k, dim3((E + 255) / 256), dim3(256), 0, stream,
                     exh, denom, ei, (float*)d_out, E);
}